// Round 6
// baseline (123.222 us; speedup 1.0000x reference)
//
#include <hip/hip_runtime.h>

typedef __attribute__((ext_vector_type(4))) int   i32x4;
typedef __attribute__((ext_vector_type(4))) float f32x4;

#define HDIM 16
#define MDIM 2048
#define NDIM 2048
#define KDIM 128

// Pack 4 int32 (values 0..126, high bytes zero) into one dword of 4 int8.
__device__ inline int pack4(i32x4 v) {
    return v.x | (v.y << 8) | (v.z << 16) | (v.w << 24);
}

// ---------------------------------------------------------------------------
// Single-pass batched i8 GEMM: C[h] = A[h] (MxK int32 0..126) * B[h]^T.
//
// Per block (128x128 tile, 4 waves 2x2):
//  1. Cooperative stage+pack: 128x128 int32 A/B tiles -> int8 in LDS.
//     Thread t, quad q covers packed bytes [q*4096 + t*16): one row-segment
//     (row = q*32 + t>>3, col = (t&7)*16) = 4x dwordx4 global (64 B
//     contiguous per lane) -> 3 VALU pack each -> 1 ds_write_b128.
//     LDS layout [kchunk=8][row=128][16 B]: write banks = (row*4)%32, read
//     banks likewise -> 8 accesses/bank = structural minimum, no swizzle.
//  2. One barrier; each wave reads 16 fragments (ds_read_b128) and runs
//     2 K-steps of v_mfma_i32_16x16x64_i8 with SWAPPED operands ->
//     lane (fr=lane&15, kg=lane>>4) holds C[m=..+fr][n=..+kg*4+r],
//     r=0..3 consecutive -> float4 coalesced stores.
//  3. Epilogue: c = clamp(rint(acc * ((sA[m]/sO[m]) * sB[n])), -127, 127)
//     stored as float32 (harness reads d_out as float32).
//
// Grid 4096 with chunked XCD swizzle (8 XCDs x 512): each XCD owns h-pair
// slabs; its L2 assembles full output rows and streams a contiguous slab.
// Blocks w<128 also copy the scale_out passthrough tail (32768 floats).
// ---------------------------------------------------------------------------
__global__ __launch_bounds__(256)
void gemm_i8_onepass(const int* __restrict__ A,
                     const int* __restrict__ B,
                     const float* __restrict__ sA,
                     const float* __restrict__ sB,
                     const float* __restrict__ sO,
                     float* __restrict__ out) {
    __shared__ unsigned char lA[8][128][16];   // 16 KB packed A tile
    __shared__ unsigned char lB[8][128][16];   // 16 KB packed B tile

    // chunked XCD swizzle: nwg = 4096, 8 XCDs, 512 per chunk
    const int i = blockIdx.x;
    const int w = (i & 7) * 512 + (i >> 3);
    const int bx = w & 15;
    const int by = (w >> 4) & 15;
    const int h  = w >> 8;

    const int tid = threadIdx.x;

    // Output 1 tail: scale_out passthrough (exact), folded into first blocks.
    if (w < 128) {
        const int t = w * 256 + tid;
        out[(size_t)HDIM * MDIM * NDIM + t] = sO[t];
    }

    const int bm = by * 128;
    const int bn = bx * 128;
    const int* Ah = A + ((size_t)h * MDIM + bm) * KDIM;
    const int* Bh = B + ((size_t)h * NDIM + bn) * KDIM;

    // ---- Stage + pack both tiles into LDS ----
    const int srow = tid >> 3;          // 0..31 (+q*32)
    const int scol = (tid & 7) * 16;    // element col, 16-aligned
#pragma unroll
    for (int q = 0; q < 4; ++q) {
        const int row = q * 32 + srow;
        const i32x4* pa = reinterpret_cast<const i32x4*>(Ah + (size_t)row * KDIM + scol);
        const i32x4* pb = reinterpret_cast<const i32x4*>(Bh + (size_t)row * KDIM + scol);
        i32x4 a0 = pa[0], a1 = pa[1], a2 = pa[2], a3 = pa[3];
        i32x4 b0 = pb[0], b1 = pb[1], b2 = pb[2], b3 = pb[3];
        i32x4 packedA = (i32x4){pack4(a0), pack4(a1), pack4(a2), pack4(a3)};
        i32x4 packedB = (i32x4){pack4(b0), pack4(b1), pack4(b2), pack4(b3)};
        *reinterpret_cast<i32x4*>(&lA[tid & 7][row][0]) = packedA;
        *reinterpret_cast<i32x4*>(&lB[tid & 7][row][0]) = packedB;
    }
    __syncthreads();

    // ---- Fragments + MFMA ----
    const int wave = tid >> 6;
    const int lane = tid & 63;
    const int wm = (wave >> 1) * 64;   // wave row offset in block tile
    const int wn = (wave & 1) * 64;    // wave col offset
    const int fr = lane & 15;          // fragment row; out row m
    const int kg = lane >> 4;          // 0..3 k-group; out n-subchunk

    i32x4 af[2][4], bf[2][4];
#pragma unroll
    for (int ks = 0; ks < 2; ++ks) {
#pragma unroll
        for (int mi = 0; mi < 4; ++mi)
            af[ks][mi] = *reinterpret_cast<const i32x4*>(&lA[ks * 4 + kg][wm + mi * 16 + fr][0]);
#pragma unroll
        for (int ni = 0; ni < 4; ++ni)
            bf[ks][ni] = *reinterpret_cast<const i32x4*>(&lB[ks * 4 + kg][wn + ni * 16 + fr][0]);
    }

    i32x4 acc[4][4];
#pragma unroll
    for (int mi = 0; mi < 4; ++mi)
#pragma unroll
        for (int ni = 0; ni < 4; ++ni)
            acc[mi][ni] = (i32x4){0, 0, 0, 0};

#pragma unroll
    for (int ks = 0; ks < 2; ++ks)
#pragma unroll
        for (int mi = 0; mi < 4; ++mi)
#pragma unroll
            for (int ni = 0; ni < 4; ++ni)
                acc[mi][ni] = __builtin_amdgcn_mfma_i32_16x16x64_i8(
                    bf[ks][ni], af[ks][mi], acc[mi][ni], 0, 0, 0);  // swapped -> C^T frag

    // ---- Epilogue: lane holds row m = bm+wm+mi*16+fr,
    // cols n = bn+wn+ni*16+kg*4 .. +3 (regs r=0..3 consecutive n). ----
    const float* sAh = sA + h * MDIM;
    const float* sBh = sB + h * NDIM;
    const float* sOh = sO + h * MDIM;

    float smv[4];
#pragma unroll
    for (int mi = 0; mi < 4; ++mi) {
        const int m = bm + wm + mi * 16 + fr;
        smv[mi] = sAh[m] / sOh[m];          // reference op order: sA/sO first
    }
    f32x4 sbv[4];
#pragma unroll
    for (int ni = 0; ni < 4; ++ni)
        sbv[ni] = *reinterpret_cast<const f32x4*>(sBh + bn + wn + ni * 16 + kg * 4);

#pragma unroll
    for (int mi = 0; mi < 4; ++mi) {
        const int m = bm + wm + mi * 16 + fr;
        float* orow = out + ((size_t)h * MDIM + m) * NDIM + bn + wn + kg * 4;
#pragma unroll
        for (int ni = 0; ni < 4; ++ni) {
            f32x4 o;
#pragma unroll
            for (int r = 0; r < 4; ++r) {
                float c = (float)acc[mi][ni][r] * (smv[mi] * sbv[ni][r]);
                float rv = rintf(c);                       // RNE == np.round
                o[r] = fminf(fmaxf(rv, -127.0f), 127.0f);
            }
            *reinterpret_cast<f32x4*>(orow + ni * 16) = o;
        }
    }
}

extern "C" void kernel_launch(void* const* d_in, const int* in_sizes, int n_in,
                              void* d_out, int out_size, void* d_ws, size_t ws_size,
                              hipStream_t stream) {
    const int*   A  = (const int*)d_in[0];
    const int*   B  = (const int*)d_in[1];
    const float* sA = (const float*)d_in[2];
    const float* sB = (const float*)d_in[3];
    const float* sO = (const float*)d_in[4];
    float* out = (float*)d_out;

    gemm_i8_onepass<<<4096, 256, 0, stream>>>(A, B, sA, sB, sO, out);
}

// Round 7
// 85.220 us; speedup vs baseline: 1.4459x; 1.4459x over previous
//
#include <hip/hip_runtime.h>

typedef __attribute__((ext_vector_type(4))) int   i32x4;
typedef __attribute__((ext_vector_type(4))) float f32x4;

#define HDIM 16
#define MDIM 2048
#define NDIM 2048
#define KDIM 128

// ---------------------------------------------------------------------------
// Prep kernel (proven r5): packs A and B (int32 0..126 -> int8, 16 elems/thr)
// and copies the scale_out passthrough tail. One launch.
// ---------------------------------------------------------------------------
__global__ __launch_bounds__(256)
void prep_pack_tail(const int* __restrict__ A,
                    const int* __restrict__ B,
                    const float* __restrict__ sO,
                    unsigned char* __restrict__ A8,
                    unsigned char* __restrict__ B8,
                    float* __restrict__ out_tail) {
    const int nPackA = HDIM * MDIM * KDIM / 16;   // 262,144 threads for A
    int t = blockIdx.x * blockDim.x + threadIdx.x;

    const int* src;
    unsigned char* dst;
    int idx;
    if (t < nPackA) { src = A; dst = A8; idx = t; }
    else            { src = B; dst = B8; idx = t - nPackA; }

    const i32x4* s = reinterpret_cast<const i32x4*>(src) + (size_t)idx * 4;
    i32x4 v0 = s[0], v1 = s[1], v2 = s[2], v3 = s[3];
    i32x4 o;
    o.x = v0.x | (v0.y << 8) | (v0.z << 16) | (v0.w << 24);
    o.y = v1.x | (v1.y << 8) | (v1.z << 16) | (v1.w << 24);
    o.z = v2.x | (v2.y << 8) | (v2.z << 16) | (v2.w << 24);
    o.w = v3.x | (v3.y << 8) | (v3.z << 16) | (v3.w << 24);
    reinterpret_cast<i32x4*>(dst)[idx] = o;

    if (t < HDIM * MDIM)                           // 32,768 tail floats
        out_tail[t] = sO[t];
}

// ---------------------------------------------------------------------------
// Batched i8 GEMM on pre-packed int8: C[h] = A[h] (MxK) * B[h]^T.
// Tile 128x256, 512 threads = 8 waves in 2x4; each wave computes the SAME
// proven 64x64 sub-tile as r5 (4x4 fragments of v_mfma_i32_16x16x64_i8,
// K = 2 unrolled steps, 16 B/lane/fragment, swapped operands -> lane
// (fr=lane&15, kg=lane>>4) holds C[m=..+fr][n=..+kg*4+r], r consecutive
// -> float4 coalesced stores). Wider tile doubles per-row write chunk to
// 1 KB and halves concurrent write streams per XCD (DRAM page locality).
//
// Grid 2048, chunked XCD swizzle (8 XCDs x 256): XCD k owns w in
// [256k, 256k+256) = 2 h's, all (by, bx), bx fastest -> its L2 assembles
// full output rows and streams a contiguous ~34 MB slab.
// Epilogue: c = clamp(rint(acc * ((sA[m]/sO[m]) * sB[n])), -127, 127),
// stored as float32 (harness reads d_out as float32).
// ---------------------------------------------------------------------------
__global__ __launch_bounds__(512)
void gemm_i8_fused(const unsigned char* __restrict__ A8,
                   const unsigned char* __restrict__ B8,
                   const float* __restrict__ sA,
                   const float* __restrict__ sB,
                   const float* __restrict__ sO,
                   float* __restrict__ out) {
    // chunked XCD swizzle: nwg = 2048, 8 XCDs, 256 per chunk
    const int i = blockIdx.x;
    const int w = (i & 7) * 256 + (i >> 3);
    const int bx = w & 7;            // 8 col-tiles of 256
    const int by = (w >> 3) & 15;    // 16 row-tiles of 128
    const int h  = w >> 7;

    const int bm = by * 128;
    const int bn = bx * 256;
    const int tid  = threadIdx.x;
    const int wave = tid >> 6;
    const int lane = tid & 63;
    const int wm = (wave >> 2) * 64;   // wave row offset in block tile (2 rows of waves)
    const int wn = (wave & 3) * 64;    // wave col offset (4 cols of waves)
    const int fr = lane & 15;          // fragment row for loads; out row m
    const int kg = lane >> 4;          // 0..3 k-group; out n-subchunk

    const unsigned char* Ah = A8 + (size_t)h * MDIM * KDIM;
    const unsigned char* Bh = B8 + (size_t)h * NDIM * KDIM;

    i32x4 acc[4][4];
#pragma unroll
    for (int mi = 0; mi < 4; ++mi)
#pragma unroll
        for (int ni = 0; ni < 4; ++ni)
            acc[mi][ni] = (i32x4){0, 0, 0, 0};

#pragma unroll
    for (int ks = 0; ks < 2; ++ks) {
        const int kb = ks * 64 + kg * 16;   // byte offset of this lane's 16B chunk
        i32x4 af[4], bf[4];
#pragma unroll
        for (int mi = 0; mi < 4; ++mi)
            af[mi] = *reinterpret_cast<const i32x4*>(
                Ah + (size_t)(bm + wm + mi * 16 + fr) * KDIM + kb);
#pragma unroll
        for (int ni = 0; ni < 4; ++ni)
            bf[ni] = *reinterpret_cast<const i32x4*>(
                Bh + (size_t)(bn + wn + ni * 16 + fr) * KDIM + kb);
#pragma unroll
        for (int mi = 0; mi < 4; ++mi)
#pragma unroll
            for (int ni = 0; ni < 4; ++ni)
                acc[mi][ni] = __builtin_amdgcn_mfma_i32_16x16x64_i8(
                    bf[ni], af[mi], acc[mi][ni], 0, 0, 0);  // swapped -> C^T frag
    }

    // Epilogue. Lane holds row m = bm+wm+mi*16+fr,
    // cols n = bn+wn+ni*16+kg*4 .. +3 (regs r=0..3 consecutive n).
    const float* sAh = sA + h * MDIM;
    const float* sBh = sB + h * NDIM;
    const float* sOh = sO + h * MDIM;

    float smv[4];
#pragma unroll
    for (int mi = 0; mi < 4; ++mi) {
        const int m = bm + wm + mi * 16 + fr;
        smv[mi] = sAh[m] / sOh[m];          // reference op order: sA/sO first
    }
    f32x4 sbv[4];
#pragma unroll
    for (int ni = 0; ni < 4; ++ni)
        sbv[ni] = *reinterpret_cast<const f32x4*>(sBh + bn + wn + ni * 16 + kg * 4);

#pragma unroll
    for (int mi = 0; mi < 4; ++mi) {
        const int m = bm + wm + mi * 16 + fr;
        float* orow = out + ((size_t)h * MDIM + m) * NDIM + bn + wn + kg * 4;
#pragma unroll
        for (int ni = 0; ni < 4; ++ni) {
            f32x4 o;
#pragma unroll
            for (int r = 0; r < 4; ++r) {
                float c = (float)acc[mi][ni][r] * (smv[mi] * sbv[ni][r]);
                float rv = rintf(c);                       // RNE == np.round
                o[r] = fminf(fmaxf(rv, -127.0f), 127.0f);
            }
            *reinterpret_cast<f32x4*>(orow + ni * 16) = o;
        }
    }
}

extern "C" void kernel_launch(void* const* d_in, const int* in_sizes, int n_in,
                              void* d_out, int out_size, void* d_ws, size_t ws_size,
                              hipStream_t stream) {
    const int*   A  = (const int*)d_in[0];
    const int*   B  = (const int*)d_in[1];
    const float* sA = (const float*)d_in[2];
    const float* sB = (const float*)d_in[3];
    const float* sO = (const float*)d_in[4];
    float* out = (float*)d_out;

    unsigned char* A8 = (unsigned char*)d_ws;
    unsigned char* B8 = A8 + (size_t)HDIM * MDIM * KDIM;

    const int packThreads = 2 * HDIM * MDIM * KDIM / 16;   // 524,288
    prep_pack_tail<<<packThreads / 256, 256, 0, stream>>>(
        A, B, sO, A8, B8, out + (size_t)HDIM * MDIM * NDIM);

    gemm_i8_fused<<<2048, 512, 0, stream>>>(A8, B8, sA, sB, sO, out);
}